// Round 1
// baseline (8102.581 us; speedup 1.0000x reference)
//
#include <hip/hip_runtime.h>

// GRU scan, 2 layers, B=64 T=4096 D=H=128 — layer-specialized waves.
// 4 persistent WGs x 16 batch rows x 512 threads (8 waves).
// Waves 0-3 compute layer 0, waves 4-7 compute layer 1 (skew 2 steps).
// Each wave owns 2 unit-groups (32 hidden units) of its layer: 96 weight
// frags stationary in VGPR/AGPR.
//
// v2 changes vs 7030us baseline:
//  * ONE barrier per step (was 2). Hazard audit: all intra-step LDS
//    read/write sets are parity-disjoint (reads at parx, writes at par);
//    the mid-barrier only protected the prologue X[0] read, now covered
//    by an extra pre-loop barrier. Merged region lets the scheduler
//    overlap gate VALU with input-MFMA issue.
//  * Bank-conflict-free h-writes via reader-matched XOR swizzle:
//    addr(row,k) = (k>>5)*512 + ((k>>3)&3)*128 + ((row^((k>>3)&3)))*8 + (k&7)
//    Reader lane l, kstep s: b128 at s*512 + quad*128 + ((lc^quad)<<3)
//    (still 64 distinct 16B slots -> conflict-free). Writer b16 stores now
//    spread over 16 banks (2-way residual = free) instead of 8 (4-way).
//  * x-stage write moved before gates (independent; retires vmcnt early).

#define Tlen 4096
#define Hd   128
#define Bsz  64

typedef __attribute__((ext_vector_type(8))) short short8;     // 8 bf16
typedef __attribute__((ext_vector_type(4))) short short4v;    // 4 bf16
typedef __attribute__((ext_vector_type(4))) float float4v;
typedef __attribute__((ext_vector_type(2))) unsigned int uint2v;

#define MFMA16(a, b, c) __builtin_amdgcn_mfma_f32_16x16x32_bf16((a), (b), (c), 0, 0, 0)

static __device__ __forceinline__ float fast_exp2(float x) {
#if __has_builtin(__builtin_amdgcn_exp2f)
  return __builtin_amdgcn_exp2f(x);
#else
  return exp2f(x);
#endif
}
static __device__ __forceinline__ float fast_rcp(float x) {
  return __builtin_amdgcn_rcpf(x);
}
static __device__ __forceinline__ short f2bf(float f) {  // RTNE fp32->bf16
  unsigned u = __builtin_bit_cast(unsigned, f);
  u = (u + 0x7FFFu + ((u >> 16) & 1u)) >> 16;
  return (short)u;
}
static __device__ __forceinline__ unsigned pk2bf(float a, float b) {  // lo=a hi=b
#if __has_builtin(__builtin_amdgcn_cvt_pk_bf16_f32)
  auto v = __builtin_amdgcn_cvt_pk_bf16_f32(a, b);
  return __builtin_bit_cast(unsigned, v);
#else
  return (unsigned)(unsigned short)f2bf(a) | ((unsigned)(unsigned short)f2bf(b) << 16);
#endif
}
static __device__ __forceinline__ short8 loadw8(const float* __restrict__ p) {
  short8 r;
  #pragma unroll
  for (int j = 0; j < 8; ++j) r[j] = f2bf(p[j]);
  return r;
}

// LDS blocks (short indices). Block = 2048 shorts (16 rows x 128 k bf16).
#define XB   0
#define H0B  4096
#define H1B  8192
#define BLK  2048

__global__ __launch_bounds__(512, 2) void gru_scan(
    const float* __restrict__ x,
    const float* __restrict__ Wih0, const float* __restrict__ Whh0,
    const float* __restrict__ bih0, const float* __restrict__ bhh0,
    const float* __restrict__ Wih1, const float* __restrict__ Whh1,
    const float* __restrict__ bih1, const float* __restrict__ bhh1,
    float* __restrict__ out) {
  __shared__ alignas(16) short Abuf[12288];  // 24 KB

  const int tid   = threadIdx.x;
  const int wave  = tid >> 6;
  const int lane  = tid & 63;
  const int lc    = lane & 15;
  const int quad  = lane >> 4;
  const int q8    = quad * 8;
  const int bbase = blockIdx.x * 16;

  const int wgrp = wave >> 2;     // 0 = layer0 waves, 1 = layer1 waves
  const int w4   = wave & 3;

  // swizzled frag-read offset: b128 at s*512 + rdoff reads
  // A[row=lc][k=32s+q8+j] under the XOR-swizzled layout.
  const int rdoff = quad * 128 + ((lc ^ quad) << 3);

  const float* Wi = wgrp ? Wih1 : Wih0;
  const float* Wh = wgrp ? Whh1 : Whh0;
  const float* bi = wgrp ? bih1 : bih0;
  const float* bh = wgrp ? bhh1 : bhh0;

  // ---- stationary weight fragments: ONE layer, 2 unit-groups -------------
  short8 fxr[2][4], fxz[2][4], fxn[2][4];   // input-side (Wih)
  short8 fhr[2][4], fhz[2][4], fhn[2][4];   // hidden-side (Whh)
  float kr[2], kz[2], ki[2], kh[2];
  const float nL  = -1.44269504088896f;     // -log2(e)
  const float n2L = -2.88539008177793f;     // -2*log2(e)
  #pragma unroll
  for (int G = 0; G < 2; ++G) {
    const int c = 32 * w4 + 16 * G + lc;    // unit (column) this lane owns
    #pragma unroll
    for (int s = 0; s < 4; ++s) {
      const int k = 32 * s + q8;
      fxr[G][s] = loadw8(Wi + (c)       * Hd + k);
      fxz[G][s] = loadw8(Wi + (128 + c) * Hd + k);
      fxn[G][s] = loadw8(Wi + (256 + c) * Hd + k);
      fhr[G][s] = loadw8(Wh + (c)       * Hd + k);
      fhz[G][s] = loadw8(Wh + (128 + c) * Hd + k);
      fhn[G][s] = loadw8(Wh + (256 + c) * Hd + k);
    }
    kr[G] = nL  * (bi[c] + bh[c]);
    kz[G] = nL  * (bi[128 + c] + bh[128 + c]);
    ki[G] = n2L * bi[256 + c];
    kh[G] = n2L * bh[256 + c];
  }

  // LDS bases per wave-group
  const int hsel = wgrp ? H1B : H0B;   // h-part read + h write
  const int isel = wgrp ? H0B : XB;    // input-part read

  // h-write base per G (swizzled layout). Unit k=c: e=(k>>3)&3=2G+(lc>>3).
  // Full addr for value (row=4q+i): (wr + hh[G]) ^ (i<<3).
  int hh[2];
  #pragma unroll
  for (int G = 0; G < 2; ++G) {
    const int e = 2 * G + (lc >> 3);
    hh[G] = w4 * 512 + e * 128 + (lc & 7) + 32 * quad + (e << 3);
  }

  // x staging slots: thread -> (row, k0..k0+3), swizzled layout
  const int xrow = tid >> 5;
  const int xk0  = 4 * (tid & 31);
  const int xe   = (xk0 >> 3) & 3;
  const int xwoff = (xk0 >> 5) * 512 + xe * 128 + ((xrow ^ xe) << 3) + (xk0 & 7);
  const float* xg = x + (size_t)(bbase + xrow) * (Tlen * Hd) + xk0;

  // gate-validity window: L0 steps t in [0,T), L1 sigma=t-2 -> t in [2,T+2)
  const int glo = wgrp ? 2 : 0;
  const int ghi = glo + Tlen;

  // ---- prologue ----------------------------------------------------------
  {
    int* zb = (int*)Abuf;               // zero H0/H1 blocks: dwords [2048,6144)
    #pragma unroll
    for (int i = 0; i < 8; ++i) zb[2048 + tid + 512 * i] = 0;
    const float4v v0 = *(const float4v*)(xg);                 // x(0)
    const float4v v1 = *(const float4v*)(xg + Hd);            // x(1)
    uint2v p0 = {pk2bf(v0[0], v0[1]), pk2bf(v0[2], v0[3])};
    uint2v p1 = {pk2bf(v1[0], v1[1]), pk2bf(v1[2], v1[3])};
    *(short4v*)&Abuf[XB + xwoff]       = __builtin_bit_cast(short4v, p0);
    *(short4v*)&Abuf[XB + BLK + xwoff] = __builtin_bit_cast(short4v, p1);
  }
  __syncthreads();

  const float4v Z4 = {0.f, 0.f, 0.f, 0.f};
  float4v ar[2], az[2], an[2], ah[2];
  float4v hp[2] = {Z4, Z4};

  // prologue "P2(-1)": input-part MFMAs (L0: x(0) from X[0]; L1: zeros)
  #pragma unroll
  for (int G = 0; G < 2; ++G) { ar[G] = Z4; az[G] = Z4; an[G] = Z4; ah[G] = Z4; }
  #pragma unroll
  for (int s = 0; s < 4; ++s) {
    const short8 a = *(const short8*)&Abuf[isel + s * 512 + rdoff];
    #pragma unroll
    for (int G = 0; G < 2; ++G) {
      ar[G] = MFMA16(a, fxr[G][s], ar[G]);
      az[G] = MFMA16(a, fxz[G][s], az[G]);
      an[G] = MFMA16(a, fxn[G][s], an[G]);
    }
  }
  // Extra barrier: the t=0 x-stage write to X[0] must not race the
  // prologue input-part reads of X[0] above (other waves).
  __syncthreads();

  // ---- main loop: T+2 iterations, ONE barrier per step -------------------
  for (int t = 0; t < Tlen + 2; ++t) {
    const int par  = (t & 1) * BLK;     // parity t block offset (writes)
    const int parx = BLK - par;         // parity (t+1) block offset (reads)

    // x(t+2) global prefetch (consumed by the stage-write below)
    const int tn = (t + 2 < Tlen) ? (t + 2) : (Tlen - 1);
    const float4v xv = *(const float4v*)(xg + (size_t)tn * Hd);

    // h-part MFMAs (24), reading h(t-1) at parity parx
    const int hrd = hsel + parx;
    #pragma unroll
    for (int s = 0; s < 4; ++s) {
      const short8 a = *(const short8*)&Abuf[hrd + s * 512 + rdoff];
      #pragma unroll
      for (int G = 0; G < 2; ++G) {
        ar[G] = MFMA16(a, fhr[G][s], ar[G]);
        az[G] = MFMA16(a, fhz[G][s], az[G]);
        ah[G] = MFMA16(a, fhn[G][s], ah[G]);
      }
    }

    // stage x(t+2) into X[par] (dead buffer; consumed at t+1).
    // Independent of gate results -> issued early, vmcnt retired pre-barrier.
    {
      uint2v pp = {pk2bf(xv[0], xv[1]), pk2bf(xv[2], xv[3])};
      *(short4v*)&Abuf[XB + par + xwoff] = __builtin_bit_cast(short4v, pp);
    }

    // gates (consume accs) + h write to parity par
    if (t >= glo && t < ghi) {
      const int wr = hsel + par;
      #pragma unroll
      for (int G = 0; G < 2; ++G) {
        const int wb = wr + hh[G];
        #pragma unroll
        for (int i = 0; i < 4; ++i) {
          const float er = fast_exp2(fmaf(ar[G][i], nL, kr[G]));
          const float rr = fast_rcp(1.0f + er);
          const float ez = fast_exp2(fmaf(az[G][i], nL, kz[G]));
          const float zz = fast_rcp(1.0f + ez);
          float vv = fmaf(rr, fmaf(ah[G][i], n2L, kh[G]),
                          fmaf(an[G][i], n2L, ki[G]));
          vv = fminf(vv, 126.0f);
          const float e2 = fast_exp2(vv);
          const float nn = (1.0f - e2) * fast_rcp(1.0f + e2);
          const float hn = fmaf(zz, hp[G][i] - nn, nn);
          hp[G][i] = hn;
          Abuf[wb ^ (i << 3)] = f2bf(hn);
        }
      }
    }

    // input-part MFMAs for next step (re-init accs, in-place)
    const int ird = isel + parx;
    #pragma unroll
    for (int G = 0; G < 2; ++G) { ar[G] = Z4; az[G] = Z4; an[G] = Z4; ah[G] = Z4; }
    #pragma unroll
    for (int s = 0; s < 4; ++s) {
      const short8 a = *(const short8*)&Abuf[ird + s * 512 + rdoff];
      #pragma unroll
      for (int G = 0; G < 2; ++G) {
        ar[G] = MFMA16(a, fxr[G][s], ar[G]);
        az[G] = MFMA16(a, fxz[G][s], az[G]);
        an[G] = MFMA16(a, fxn[G][s], an[G]);
      }
    }
    __syncthreads();
  }

  // ---- output: L0 waves hold h0(T-1), L1 waves hold h1(T-1) --------------
  #pragma unroll
  for (int G = 0; G < 2; ++G) {
    const int u = 32 * w4 + 16 * G + lc;
    #pragma unroll
    for (int i = 0; i < 4; ++i) {
      const int b = bbase + quad * 4 + i;
      out[wgrp * (Bsz * Hd) + b * Hd + u] = hp[G][i];
    }
  }
}

extern "C" void kernel_launch(void* const* d_in, const int* in_sizes, int n_in,
                              void* d_out, int out_size, void* d_ws, size_t ws_size,
                              hipStream_t stream) {
  (void)in_sizes; (void)n_in; (void)out_size; (void)d_ws; (void)ws_size;
  gru_scan<<<4, 512, 0, stream>>>(
      (const float*)d_in[0],
      (const float*)d_in[1], (const float*)d_in[2],
      (const float*)d_in[3], (const float*)d_in[4],
      (const float*)d_in[5], (const float*)d_in[6],
      (const float*)d_in[7], (const float*)d_in[8],
      (float*)d_out);
}

// Round 2
// 7331.297 us; speedup vs baseline: 1.1052x; 1.1052x over previous
//
#include <hip/hip_runtime.h>

// GRU scan, 2 layers, B=64 T=4096 D=H=128 — layer-specialized waves.
// 4 persistent WGs x 16 batch rows x 512 threads (8 waves).
// Waves 0-3 compute layer 0, waves 4-7 compute layer 1 (skew 2 steps).
// Each wave owns 2 unit-groups (32 hidden units) of its layer: 96 weight
// frags stationary in VGPR/AGPR.
// Per step, per wave: P1 = 24 h-part MFMAs; P2 = gates + 24 input-part MFMAs.
//
// v3 = v1 (7030us two-barrier schedule) + XOR-swizzled LDS layout only.
// Round-1 A/B showed the barrier merge REGRESSED (-550cy/step): the
// mid-barrier absorbs MFMA->VALU hazard latency and keeps the 2 waves/SIMD
// in complementary pipe phases. The swizzle itself verified correct and cut
// SQ_LDS_BANK_CONFLICT 11x. This round isolates the swizzle on the
// known-good schedule.
//
// Swizzled layout: addr(row,k) = (k>>5)*512 + e*128 + ((row^e)<<3) + (k&7),
// e=(k>>3)&3. Reader lane l, kstep s: b128 at s*512 + quad*128 + ((lc^quad)<<3)
// (64 distinct 16B slots -> conflict-free). Writer b16 h-stores spread over
// 16 banks (2-way residual = free) instead of 8 (4-way).

#define Tlen 4096
#define Hd   128
#define Bsz  64

typedef __attribute__((ext_vector_type(8))) short short8;     // 8 bf16
typedef __attribute__((ext_vector_type(4))) short short4v;    // 4 bf16
typedef __attribute__((ext_vector_type(4))) float float4v;
typedef __attribute__((ext_vector_type(2))) unsigned int uint2v;

#define MFMA16(a, b, c) __builtin_amdgcn_mfma_f32_16x16x32_bf16((a), (b), (c), 0, 0, 0)

static __device__ __forceinline__ float fast_exp2(float x) {
#if __has_builtin(__builtin_amdgcn_exp2f)
  return __builtin_amdgcn_exp2f(x);
#else
  return exp2f(x);
#endif
}
static __device__ __forceinline__ float fast_rcp(float x) {
  return __builtin_amdgcn_rcpf(x);
}
static __device__ __forceinline__ short f2bf(float f) {  // RTNE fp32->bf16
  unsigned u = __builtin_bit_cast(unsigned, f);
  u = (u + 0x7FFFu + ((u >> 16) & 1u)) >> 16;
  return (short)u;
}
static __device__ __forceinline__ unsigned pk2bf(float a, float b) {  // lo=a hi=b
#if __has_builtin(__builtin_amdgcn_cvt_pk_bf16_f32)
  auto v = __builtin_amdgcn_cvt_pk_bf16_f32(a, b);
  return __builtin_bit_cast(unsigned, v);
#else
  return (unsigned)(unsigned short)f2bf(a) | ((unsigned)(unsigned short)f2bf(b) << 16);
#endif
}
static __device__ __forceinline__ short8 loadw8(const float* __restrict__ p) {
  short8 r;
  #pragma unroll
  for (int j = 0; j < 8; ++j) r[j] = f2bf(p[j]);
  return r;
}

// LDS blocks (short indices). Block = 2048 shorts (16 rows x 128 k bf16).
#define XB   0
#define H0B  4096
#define H1B  8192
#define BLK  2048

__global__ __launch_bounds__(512, 2) void gru_scan(
    const float* __restrict__ x,
    const float* __restrict__ Wih0, const float* __restrict__ Whh0,
    const float* __restrict__ bih0, const float* __restrict__ bhh0,
    const float* __restrict__ Wih1, const float* __restrict__ Whh1,
    const float* __restrict__ bih1, const float* __restrict__ bhh1,
    float* __restrict__ out) {
  __shared__ alignas(16) short Abuf[12288];  // 24 KB

  const int tid   = threadIdx.x;
  const int wave  = tid >> 6;
  const int lane  = tid & 63;
  const int lc    = lane & 15;
  const int quad  = lane >> 4;
  const int q8    = quad * 8;
  const int bbase = blockIdx.x * 16;

  const int wgrp = wave >> 2;     // 0 = layer0 waves, 1 = layer1 waves
  const int w4   = wave & 3;

  // swizzled frag-read offset: b128 at s*512 + rdoff reads
  // A[row=lc][k=32s+q8+j] under the XOR-swizzled layout.
  const int rdoff = quad * 128 + ((lc ^ quad) << 3);

  const float* Wi = wgrp ? Wih1 : Wih0;
  const float* Wh = wgrp ? Whh1 : Whh0;
  const float* bi = wgrp ? bih1 : bih0;
  const float* bh = wgrp ? bhh1 : bhh0;

  // ---- stationary weight fragments: ONE layer, 2 unit-groups -------------
  short8 fxr[2][4], fxz[2][4], fxn[2][4];   // input-side (Wih)
  short8 fhr[2][4], fhz[2][4], fhn[2][4];   // hidden-side (Whh)
  float kr[2], kz[2], ki[2], kh[2];
  const float nL  = -1.44269504088896f;     // -log2(e)
  const float n2L = -2.88539008177793f;     // -2*log2(e)
  #pragma unroll
  for (int G = 0; G < 2; ++G) {
    const int c = 32 * w4 + 16 * G + lc;    // unit (column) this lane owns
    #pragma unroll
    for (int s = 0; s < 4; ++s) {
      const int k = 32 * s + q8;
      fxr[G][s] = loadw8(Wi + (c)       * Hd + k);
      fxz[G][s] = loadw8(Wi + (128 + c) * Hd + k);
      fxn[G][s] = loadw8(Wi + (256 + c) * Hd + k);
      fhr[G][s] = loadw8(Wh + (c)       * Hd + k);
      fhz[G][s] = loadw8(Wh + (128 + c) * Hd + k);
      fhn[G][s] = loadw8(Wh + (256 + c) * Hd + k);
    }
    kr[G] = nL  * (bi[c] + bh[c]);
    kz[G] = nL  * (bi[128 + c] + bh[128 + c]);
    ki[G] = n2L * bi[256 + c];
    kh[G] = n2L * bh[256 + c];
  }

  // LDS bases per wave-group
  const int hsel = wgrp ? H1B : H0B;   // h-part read (P1) + h write (P2)
  const int isel = wgrp ? H0B : XB;    // input-part read (P2)

  // h-write base per G (swizzled layout). Unit k=c: e=(k>>3)&3 = 2G+(lc>>3).
  // Full addr for value (row=4*quad+i): (wr + hh[G]) ^ (i<<3)  [no carries:
  // bits[3:5) of wr+hh[G] are exactly e, i<<3 occupies the same bits].
  int hh[2];
  #pragma unroll
  for (int G = 0; G < 2; ++G) {
    const int e = 2 * G + (lc >> 3);
    hh[G] = w4 * 512 + e * 128 + (lc & 7) + 32 * quad + (e << 3);
  }

  // x staging slots: thread -> (row, k0..k0+3), swizzled layout
  const int xrow = tid >> 5;
  const int xk0  = 4 * (tid & 31);
  const int xe   = (xk0 >> 3) & 3;
  const int xwoff = (xk0 >> 5) * 512 + xe * 128 + ((xrow ^ xe) << 3) + (xk0 & 7);
  const float* xg = x + (size_t)(bbase + xrow) * (Tlen * Hd) + xk0;

  // gate-validity window: L0 steps t in [0,T), L1 sigma=t-2 -> t in [2,T+2)
  const int glo = wgrp ? 2 : 0;
  const int ghi = glo + Tlen;

  // ---- prologue ----------------------------------------------------------
  {
    int* zb = (int*)Abuf;               // zero H0/H1 blocks: dwords [2048,6144)
    #pragma unroll
    for (int i = 0; i < 8; ++i) zb[2048 + tid + 512 * i] = 0;
    const float4v v0 = *(const float4v*)(xg);                 // x(0)
    const float4v v1 = *(const float4v*)(xg + Hd);            // x(1)
    uint2v p0 = {pk2bf(v0[0], v0[1]), pk2bf(v0[2], v0[3])};
    uint2v p1 = {pk2bf(v1[0], v1[1]), pk2bf(v1[2], v1[3])};
    *(short4v*)&Abuf[XB + xwoff]       = __builtin_bit_cast(short4v, p0);
    *(short4v*)&Abuf[XB + BLK + xwoff] = __builtin_bit_cast(short4v, p1);
  }
  __syncthreads();

  const float4v Z4 = {0.f, 0.f, 0.f, 0.f};
  float4v ar[2], az[2], an[2], ah[2];
  float4v hp[2] = {Z4, Z4};

  // prologue "P2(-1)": input-part MFMAs (L0: x(0) from X[0]; L1: zeros)
  #pragma unroll
  for (int G = 0; G < 2; ++G) { ar[G] = Z4; az[G] = Z4; an[G] = Z4; ah[G] = Z4; }
  #pragma unroll
  for (int s = 0; s < 4; ++s) {
    const short8 a = *(const short8*)&Abuf[isel + s * 512 + rdoff];
    #pragma unroll
    for (int G = 0; G < 2; ++G) {
      ar[G] = MFMA16(a, fxr[G][s], ar[G]);
      az[G] = MFMA16(a, fxz[G][s], az[G]);
      an[G] = MFMA16(a, fxn[G][s], an[G]);
    }
  }

  // ---- main loop: T+2 iterations (2-step drain for layer 1) --------------
  for (int t = 0; t < Tlen + 2; ++t) {
    const int par  = (t & 1) * BLK;     // parity t block offset
    const int parx = BLK - par;         // parity (t+1) block offset

    // ---- P1: h-part MFMAs (24) + x(t+2) global prefetch ----
    const int tn = (t + 2 < Tlen) ? (t + 2) : (Tlen - 1);
    const float4v xv = *(const float4v*)(xg + (size_t)tn * Hd);
    const int hrd = hsel + parx;
    #pragma unroll
    for (int s = 0; s < 4; ++s) {
      const short8 a = *(const short8*)&Abuf[hrd + s * 512 + rdoff];
      #pragma unroll
      for (int G = 0; G < 2; ++G) {
        ar[G] = MFMA16(a, fhr[G][s], ar[G]);
        az[G] = MFMA16(a, fhz[G][s], az[G]);
        ah[G] = MFMA16(a, fhn[G][s], ah[G]);
      }
    }
    __syncthreads();

    // ---- P2: gates (consume accs) + h write + x stage + input MFMAs ----
    if (t >= glo && t < ghi) {
      const int wr = hsel + par;
      #pragma unroll
      for (int G = 0; G < 2; ++G) {
        const int wb = wr + hh[G];
        #pragma unroll
        for (int i = 0; i < 4; ++i) {
          const float er = fast_exp2(fmaf(ar[G][i], nL, kr[G]));
          const float rr = fast_rcp(1.0f + er);
          const float ez = fast_exp2(fmaf(az[G][i], nL, kz[G]));
          const float zz = fast_rcp(1.0f + ez);
          float vv = fmaf(rr, fmaf(ah[G][i], n2L, kh[G]),
                          fmaf(an[G][i], n2L, ki[G]));
          vv = fminf(vv, 126.0f);
          const float e2 = fast_exp2(vv);
          const float nn = (1.0f - e2) * fast_rcp(1.0f + e2);
          const float hn = fmaf(zz, hp[G][i] - nn, nn);
          hp[G][i] = hn;
          Abuf[wb ^ (i << 3)] = f2bf(hn);
        }
      }
    }
    {  // stage x(t+2) into X[t&1] (dead buffer; consumed in P2(t+2))
      uint2v pp = {pk2bf(xv[0], xv[1]), pk2bf(xv[2], xv[3])};
      *(short4v*)&Abuf[XB + par + xwoff] = __builtin_bit_cast(short4v, pp);
    }
    // input-part MFMAs for next step (re-init accs)
    const int ird = isel + parx;
    #pragma unroll
    for (int G = 0; G < 2; ++G) { ar[G] = Z4; az[G] = Z4; an[G] = Z4; ah[G] = Z4; }
    #pragma unroll
    for (int s = 0; s < 4; ++s) {
      const short8 a = *(const short8*)&Abuf[ird + s * 512 + rdoff];
      #pragma unroll
      for (int G = 0; G < 2; ++G) {
        ar[G] = MFMA16(a, fxr[G][s], ar[G]);
        az[G] = MFMA16(a, fxz[G][s], az[G]);
        an[G] = MFMA16(a, fxn[G][s], an[G]);
      }
    }
    __syncthreads();
  }

  // ---- output: L0 waves hold h0(T-1), L1 waves hold h1(T-1) --------------
  #pragma unroll
  for (int G = 0; G < 2; ++G) {
    const int u = 32 * w4 + 16 * G + lc;
    #pragma unroll
    for (int i = 0; i < 4; ++i) {
      const int b = bbase + quad * 4 + i;
      out[wgrp * (Bsz * Hd) + b * Hd + u] = hp[G][i];
    }
  }
}

extern "C" void kernel_launch(void* const* d_in, const int* in_sizes, int n_in,
                              void* d_out, int out_size, void* d_ws, size_t ws_size,
                              hipStream_t stream) {
  (void)in_sizes; (void)n_in; (void)out_size; (void)d_ws; (void)ws_size;
  gru_scan<<<4, 512, 0, stream>>>(
      (const float*)d_in[0],
      (const float*)d_in[1], (const float*)d_in[2],
      (const float*)d_in[3], (const float*)d_in[4],
      (const float*)d_in[5], (const float*)d_in[6],
      (const float*)d_in[7], (const float*)d_in[8],
      (float*)d_out);
}